// Round 8
// baseline (938.320 us; speedup 1.0000x reference)
//
#include <hip/hip_runtime.h>
#include <stdint.h>

typedef __bf16 bf16;
typedef __bf16   bf16x4 __attribute__((ext_vector_type(4)));
typedef short    s16x8  __attribute__((ext_vector_type(8)));
typedef float    fx4    __attribute__((ext_vector_type(4)));

#define NB 32
#define NT 1500
#define NF 512
#define NM (NB*NT)      // 48000
#define KW 31
#define EPSF 1e-5f

__device__ __forceinline__ float dscale(const float* a) {
  return fmaxf(a[0] * (1.0f/127.0f), 1e-8f);
}
__device__ __forceinline__ float fq_int(float x, float inv_s) {
  return fminf(fmaxf(rintf(x*inv_s), -128.0f), 127.0f);
}
__device__ __forceinline__ void block_amax(float v, float* dst) {
  __shared__ float red[8];
  #pragma unroll
  for (int o = 32; o > 0; o >>= 1) v = fmaxf(v, __shfl_xor(v, o));
  if ((threadIdx.x & 63) == 0) red[threadIdx.x >> 6] = v;
  __syncthreads();
  if (threadIdx.x == 0) {
    int nw = blockDim.x >> 6;
    float m = red[0];
    for (int i = 1; i < nw; i++) m = fmaxf(m, red[i]);
    atomicMax((unsigned int*)dst, __float_as_uint(m));
  }
}

__device__ __forceinline__ float amax_loop(const float* p, long n4, int bid, int gsz) {
  float am = 0.f;
  long i = (long)bid * blockDim.x + threadIdx.x;
  long stride = (long)gsz * blockDim.x;
  for (; i < n4; i += stride) {
    fx4 v = ((const fx4*)p)[i];
    #pragma unroll
    for (int j = 0; j < 4; j++) am = fmaxf(am, fabsf(v[j]));
  }
  return am;
}
// ---------- merged weight absmax (W1, W2, dw) ----------
__global__ void absmax_w(const float* __restrict__ W1, const float* __restrict__ W2,
                         const float* __restrict__ dwp, float* a) {
  int bx = blockIdx.x;
  float am; float* dst;
  if (bx < 256)      { am = amax_loop(W1,  131072, bx,       256); dst = a + 1; }
  else if (bx < 384) { am = amax_loop(W2,  65536,  bx - 256, 128); dst = a + 2; }
  else               { am = amax_loop(dwp, 3968,   bx - 384, 8);   dst = a + 3; }
  block_amax(am, dst);
}
// ---------- merged weight quantize ----------
__global__ void quant_w(const float* __restrict__ W1, const float* __restrict__ W2,
                        bf16* __restrict__ W1q, bf16* __restrict__ W2q, const float* a) {
  int bx = blockIdx.x;
  const float* src; bf16* dst; long n4; int bid, gsz; float inv_s;
  if (bx < 256) { src = W1; dst = W1q; n4 = 131072; bid = bx;     gsz = 256; inv_s = 1.0f/dscale(a+1); }
  else          { src = W2; dst = W2q; n4 = 65536;  bid = bx-256; gsz = 128; inv_s = 1.0f/dscale(a+2); }
  long i = (long)bid * blockDim.x + threadIdx.x;
  long stride = (long)gsz * blockDim.x;
  for (; i < n4; i += stride) {
    fx4 v = ((const fx4*)src)[i];
    bf16x4 o;
    #pragma unroll
    for (int j = 0; j < 4; j++) o[j] = (bf16)fq_int(v[j], inv_s);
    ((bf16x4*)dst)[i] = o;
  }
}

// ---------- quantize fp32 -> integer-grid bf16 ----------
__global__ void quant_int_f2b(const float* __restrict__ src, bf16* __restrict__ dst,
                              long n4, const float* amax) {
  float inv_s = 1.0f / dscale(amax);
  long i = (long)blockIdx.x * blockDim.x + threadIdx.x;
  long stride = (long)gridDim.x * blockDim.x;
  for (; i < n4; i += stride) {
    fx4 v = ((const fx4*)src)[i];
    bf16x4 o;
    #pragma unroll
    for (int j = 0; j < 4; j++) o[j] = (bf16)fq_int(v[j], inv_s);
    ((bf16x4*)dst)[i] = o;
  }
}
// ---------- final fake-quant fp32 in place ----------
__global__ void quant_deq_f32(float* __restrict__ p, long n4, const float* amax) {
  float s = dscale(amax);
  float inv_s = 1.0f / s;
  long i = (long)blockIdx.x * blockDim.x + threadIdx.x;
  long stride = (long)gridDim.x * blockDim.x;
  for (; i < n4; i += stride) {
    fx4 v = ((fx4*)p)[i];
    fx4 o;
    #pragma unroll
    for (int j = 0; j < 4; j++) o[j] = fq_int(v[j], inv_s) * s;
    ((fx4*)p)[i] = o;
  }
}

// ---------- LayerNorm ----------
__global__ void ln_k(const float* __restrict__ x, const float* __restrict__ g,
                     const float* __restrict__ be, float* __restrict__ t, float* amax) {
  int lane = threadIdx.x & 63;
  int wavesTotal = (gridDim.x * blockDim.x) >> 6;
  int wave = ((blockIdx.x * blockDim.x) + threadIdx.x) >> 6;
  fx4 g0 = ((const fx4*)g)[lane],  g1 = ((const fx4*)g)[lane+64];
  fx4 b0 = ((const fx4*)be)[lane], b1v = ((const fx4*)be)[lane+64];
  float gf[8], bff[8];
  #pragma unroll
  for (int j = 0; j < 4; j++) { gf[j] = g0[j]; gf[4+j] = g1[j]; bff[j] = b0[j]; bff[4+j] = b1v[j]; }
  float am = 0.f;
  for (int row = wave; row < NM; row += wavesTotal) {
    const fx4* xr = (const fx4*)(x + (long)row*NF);
    fx4 x0 = xr[lane], x1 = xr[lane+64];
    float xf[8]; float s = 0.f;
    #pragma unroll
    for (int j = 0; j < 4; j++) { xf[j] = x0[j]; xf[4+j] = x1[j]; }
    #pragma unroll
    for (int j = 0; j < 8; j++) s += xf[j];
    #pragma unroll
    for (int o = 32; o > 0; o >>= 1) s += __shfl_xor(s, o);
    float mu = s * (1.0f/NF);
    float vs = 0.f;
    #pragma unroll
    for (int j = 0; j < 8; j++) { float d = xf[j]-mu; vs += d*d; }
    #pragma unroll
    for (int o = 32; o > 0; o >>= 1) vs += __shfl_xor(vs, o);
    float inv = rsqrtf(vs*(1.0f/NF) + EPSF);
    fx4 o0, o1;
    #pragma unroll
    for (int j = 0; j < 4; j++) {
      float v = (xf[j]-mu)*inv*gf[j] + bff[j];
      am = fmaxf(am, fabsf(v)); o0[j] = v;
    }
    #pragma unroll
    for (int j = 0; j < 4; j++) {
      float v = (xf[4+j]-mu)*inv*gf[4+j] + bff[4+j];
      am = fmaxf(am, fabsf(v)); o1[j] = v;
    }
    ((fx4*)(t + (long)row*NF))[lane]    = o0;
    ((fx4*)(t + (long)row*NF))[lane+64] = o1;
  }
  block_amax(am, amax);
}

// ---------- MFMA GEMM, direct global->VGPR fragments, 512 threads, 64x32/wave ----
// Occupancy experiment: halve per-wave registers (acc 32 + frags 24) so 6-8
// waves/SIMD can cover the ~200-600cyc fragment-load latency (R7: 3 waves, 83% stall).
// C[M,N] = (qA @ qBt^T)*sa*sb + bias. A[M,512], Bt[N,512] int-grid bf16, K-major.
template<int N, int NBN>
__global__ __launch_bounds__(512) void gemm_k(
    const bf16* __restrict__ A, const bf16* __restrict__ Bt,
    const float* __restrict__ bias, float* __restrict__ C,
    const float* amaxA, const float* amaxB, float* amaxC) {
  const int K = 512;
  int id = blockIdx.x;
  int r8 = id & 7;
  int bn = (id >> 3) % NBN;
  int bm = 8 * (id / (8 * NBN)) + r8;
  if (bm >= 375) return;
  int tid = threadIdx.x;
  int lane = tid & 63;
  int w = tid >> 6;          // 0..7
  int wm = w >> 2;           // 0..1  (row group of 64)
  int wn = w & 3;            // 0..3  (col group of 32)
  int quad = lane >> 4;
  int m16 = lane & 15;

  fx4 acc[4][2];
  #pragma unroll
  for (int i = 0; i < 4; i++)
    #pragma unroll
    for (int j = 0; j < 2; j++) acc[i][j] = fx4{0.f,0.f,0.f,0.f};

  const bf16* pA[4];
  const bf16* pB[2];
  #pragma unroll
  for (int i = 0; i < 4; i++)
    pA[i] = A + (size_t)(bm*128 + wm*64 + i*16 + m16)*K + quad*8;
  #pragma unroll
  for (int j = 0; j < 2; j++)
    pB[j] = Bt + (size_t)(bn*128 + wn*32 + j*16 + m16)*K + quad*8;

  #pragma unroll
  for (int k0 = 0; k0 < K; k0 += 32) {
    s16x8 aF[4], bF[2];
    #pragma unroll
    for (int i = 0; i < 4; i++) aF[i] = *(const s16x8*)(pA[i] + k0);
    #pragma unroll
    for (int j = 0; j < 2; j++) bF[j] = *(const s16x8*)(pB[j] + k0);
    #pragma unroll
    for (int i = 0; i < 4; i++)
      #pragma unroll
      for (int j = 0; j < 2; j++)
        acc[i][j] = __builtin_amdgcn_mfma_f32_16x16x32_bf16(aF[i], bF[j], acc[i][j], 0, 0, 0);
  }

  float ab = dscale(amaxA) * dscale(amaxB);
  float am = 0.f;
  #pragma unroll
  for (int j = 0; j < 2; j++) {
    int col = bn*128 + wn*32 + j*16 + m16;
    float bv = bias[col];
    #pragma unroll
    for (int i = 0; i < 4; i++) {
      int row0 = bm*128 + wm*64 + i*16 + quad*4;
      #pragma unroll
      for (int rr = 0; rr < 4; rr++) {
        float v = acc[i][j][rr]*ab + bv;
        am = fmaxf(am, fabsf(v));
        C[(long)(row0+rr)*N + col] = v;
      }
    }
  }
  block_amax(am, amaxC);
}

// ---------- GLU + transpose [BT,1024] -> v[B,F,T] ----------
__global__ void glu_k(const float* __restrict__ u, float* __restrict__ v,
                      const float* amaxU, float* amaxV) {
  __shared__ float lds[32][33];
  float s = dscale(amaxU);
  float inv_s = 1.0f / s;
  float am = 0.f;
  int tx = threadIdx.x & 31, ty = threadIdx.x >> 5;   // 32 x 8
  const int ntile = (NM/32) * (NF/32);
  for (int tile = blockIdx.x; tile < ntile; tile += gridDim.x) {
    int btT = tile % (NM/32), fT = tile / (NM/32);
    int bt0 = btT*32, f0 = fT*32;
    __syncthreads();
    #pragma unroll
    for (int sI = 0; sI < 4; sI++) {
      int rr = ty + sI*8;
      long base = (long)(bt0 + rr)*(2*NF) + f0 + tx;
      float a = fq_int(u[base], inv_s) * s;
      float g = fq_int(u[base + NF], inv_s) * s;
      float val = a * (1.0f/(1.0f + expf(-g)));
      lds[tx][rr] = val;
      am = fmaxf(am, fabsf(val));
    }
    __syncthreads();
    #pragma unroll
    for (int sI = 0; sI < 4; sI++) {
      int f = f0 + ty + sI*8;
      int bt = bt0 + tx;
      int b = bt / NT, t = bt - b*NT;
      v[((long)b*NF + f)*NT + t] = lds[ty + sI*8][tx];
    }
  }
  block_amax(am, amaxV);
}

// ---------- depthwise conv K=31 on [B,F,T] ----------
__global__ void dwconv_k(const float* __restrict__ v, const float* __restrict__ w,
                         const float* __restrict__ wb, float* __restrict__ y,
                         const float* amaxV, const float* amaxW, float* amaxY) {
  __shared__ float z[NT + KW - 1];
  __shared__ float wl[KW];
  float sv = dscale(amaxV); float inv_sv = 1.0f/sv;
  float sw = dscale(amaxW); float inv_sw = 1.0f/sw;
  float am = 0.f;
  for (int row = blockIdx.x; row < NB*NF; row += gridDim.x) {
    int f = row & (NF-1);
    __syncthreads();
    if (threadIdx.x < KW)
      wl[threadIdx.x] = fq_int(w[f*KW + threadIdx.x], inv_sw) * sw;
    long base = (long)row * NT;
    for (int i = threadIdx.x; i < NT + KW - 1; i += 256) {
      int t = i - (KW-1)/2;
      float val = 0.f;
      if (t >= 0 && t < NT) val = fq_int(v[base + t], inv_sv) * sv;
      z[i] = val;
    }
    __syncthreads();
    float bias = wb[f];
    for (int t = threadIdx.x; t < NT; t += 256) {
      float acc = 0.f;
      #pragma unroll
      for (int k = 0; k < KW; k++) acc += z[t + k] * wl[k];
      acc += bias;
      am = fmaxf(am, fabsf(acc));
      y[base + t] = acc;
    }
  }
  block_amax(am, amaxY);
}

// ---------- BN stats: single pass, EXACT integer sums of quantized values ----------
__global__ void bnstats_k(const float* __restrict__ y, const float* amaxY,
                          float* bn_mean, float* bn_rinv) {
  float sy = dscale(amaxY); float inv_sy = 1.0f/sy;
  int f = blockIdx.x;
  int s1 = 0, s2 = 0;
  for (int b = 0; b < NB; b++) {
    const fx4* base = (const fx4*)(y + ((long)b*NF + f)*NT);
    for (int i = threadIdx.x; i < NT/4; i += blockDim.x) {
      fx4 v = base[i];
      #pragma unroll
      for (int j = 0; j < 4; j++) {
        int q = (int)fq_int(v[j], inv_sy);
        s1 += q; s2 += q*q;
      }
    }
  }
  #pragma unroll
  for (int o = 32; o > 0; o >>= 1) { s1 += __shfl_xor(s1, o); s2 += __shfl_xor(s2, o); }
  __shared__ int rs1[4], rs2[4];
  if ((threadIdx.x & 63) == 0) { rs1[threadIdx.x>>6] = s1; rs2[threadIdx.x>>6] = s2; }
  __syncthreads();
  if (threadIdx.x == 0) {
    long long S1 = (long long)rs1[0]+rs1[1]+rs1[2]+rs1[3];
    long long S2 = (long long)rs2[0]+rs2[1]+rs2[2]+rs2[3];
    double s = (double)sy;
    double mean = (double)S1 * s / (double)NM;
    double var  = (double)S2 * s * s / (double)NM - mean*mean;
    bn_mean[f] = (float)mean;
    bn_rinv[f] = rsqrtf((float)var + EPSF);
  }
}

// ---------- BN apply + silu + transpose [B,F,T] -> p[BT,F] ----------
__global__ void bnsilu_k(const float* __restrict__ y, const float* __restrict__ bg,
                         const float* __restrict__ bb, const float* amaxY,
                         const float* bn_mean, const float* bn_rinv,
                         float* __restrict__ p, float* amaxP) {
  __shared__ float lds[32][33];
  float sy = dscale(amaxY); float inv_sy = 1.0f/sy;
  float am = 0.f;
  int tx = threadIdx.x & 31, ty = threadIdx.x >> 5;
  const int TTILES = (NT + 31)/32;
  const int ntile = NB * (NF/32) * TTILES;
  for (int tile = blockIdx.x; tile < ntile; tile += gridDim.x) {
    int b = tile / ((NF/32)*TTILES);
    int rem = tile % ((NF/32)*TTILES);
    int fT = rem / TTILES, tT = rem % TTILES;
    int f0 = fT*32, t0 = tT*32;
    __syncthreads();
    #pragma unroll
    for (int sI = 0; sI < 4; sI++) {
      int f = f0 + ty + sI*8;
      int t = t0 + tx;
      if (t < NT) {
        float zq = fq_int(y[((long)b*NF + f)*NT + t], inv_sy) * sy;
        float val = (zq - bn_mean[f])*bn_rinv[f]*bg[f] + bb[f];
        val = val / (1.0f + expf(-val));
        am = fmaxf(am, fabsf(val));
        lds[tx][ty + sI*8] = val;
      }
    }
    __syncthreads();
    #pragma unroll
    for (int sI = 0; sI < 4; sI++) {
      int t = t0 + ty + sI*8;
      if (t < NT)
        p[((long)b*NT + t)*NF + f0 + tx] = lds[ty + sI*8][tx];
    }
  }
  block_amax(am, amaxP);
}

extern "C" void kernel_launch(void* const* d_in, const int* in_sizes, int n_in,
                              void* d_out, int out_size, void* d_ws, size_t ws_size,
                              hipStream_t stream) {
  const float* x  = (const float*)d_in[0];
  const float* lg = (const float*)d_in[1];
  const float* lb = (const float*)d_in[2];
  const float* W1 = (const float*)d_in[3];
  const float* b1 = (const float*)d_in[4];
  const float* dw = (const float*)d_in[5];
  const float* db = (const float*)d_in[6];
  const float* bg = (const float*)d_in[7];
  const float* bb = (const float*)d_in[8];
  const float* W2 = (const float*)d_in[9];
  const float* b2 = (const float*)d_in[10];
  float* out = (float*)d_out;

  char* ws = (char*)d_ws;
  float* amax    = (float*)ws;             // [0]=t [1]=W1 [2]=W2 [3]=dw [4]=u [5]=v [6]=y [7]=p [8]=r
  float* bn_mean = (float*)(ws + 1024);
  float* bn_rinv = (float*)(ws + 4096);
  char* H = ws + 8192;
  float* t_raw = (float*)H;                       // dies after quant
  float* u_raw = (float*)H;                       // [0, 196.6M)
  bf16*  t_q   = (bf16*)(H + 196608000);
  float* y     = (float*)H;                       // over dead u
  float* p_raw = (float*)(H + 98304000);
  bf16*  p_q   = (bf16*)(H + 196608000);          // over dead t_q
  bf16*  W1q   = (bf16*)(H + 245760000);
  bf16*  W2q   = (bf16*)(H + 246808576);
  float* v = (float*)d_out;
  float* r = (float*)d_out;

  hipMemsetAsync(ws, 0, 8192, stream);

  absmax_w<<<392, 256, 0, stream>>>(W1, W2, dw, amax);
  quant_w<<<384, 256, 0, stream>>>(W1, W2, W1q, W2q, amax);

  ln_k<<<1536, 256, 0, stream>>>(x, lg, lb, t_raw, amax+0);
  quant_int_f2b<<<2048, 256, 0, stream>>>(t_raw, t_q, 24576000/4, amax+0);
  gemm_k<1024,8><<<3008, 512, 0, stream>>>(t_q, W1q, b1, u_raw, amax+0, amax+1, amax+4);
  glu_k<<<4096, 256, 0, stream>>>(u_raw, v, amax+4, amax+5);
  dwconv_k<<<2048, 256, 0, stream>>>(v, dw, db, y, amax+5, amax+3, amax+6);
  bnstats_k<<<512, 256, 0, stream>>>(y, amax+6, bn_mean, bn_rinv);
  bnsilu_k<<<4096, 256, 0, stream>>>(y, bg, bb, amax+6, bn_mean, bn_rinv, p_raw, amax+7);
  quant_int_f2b<<<2048, 256, 0, stream>>>(p_raw, p_q, 24576000/4, amax+7);
  gemm_k<512,4><<<1504, 512, 0, stream>>>(p_q, W2q, b2, r, amax+7, amax+2, amax+8);
  quant_deq_f32<<<2048, 256, 0, stream>>>(out, 24576000/4, amax+8);
}

// Round 9
// 697.770 us; speedup vs baseline: 1.3447x; 1.3447x over previous
//
#include <hip/hip_runtime.h>
#include <stdint.h>

typedef __bf16 bf16;
typedef __bf16   bf16x4 __attribute__((ext_vector_type(4)));
typedef __bf16   bf16x8 __attribute__((ext_vector_type(8)));
typedef short    s16x8  __attribute__((ext_vector_type(8)));
typedef float    fx4    __attribute__((ext_vector_type(4)));

#define NB 32
#define NT 1500
#define NF 512
#define NM (NB*NT)      // 48000
#define KW 31
#define EPSF 1e-5f

__device__ __forceinline__ float dscale(const float* a) {
  return fmaxf(a[0] * (1.0f/127.0f), 1e-8f);
}
__device__ __forceinline__ float fq_int(float x, float inv_s) {
  return fminf(fmaxf(rintf(x*inv_s), -128.0f), 127.0f);
}
__device__ __forceinline__ void block_amax(float v, float* dst) {
  __shared__ float red[8];
  #pragma unroll
  for (int o = 32; o > 0; o >>= 1) v = fmaxf(v, __shfl_xor(v, o));
  if ((threadIdx.x & 63) == 0) red[threadIdx.x >> 6] = v;
  __syncthreads();
  if (threadIdx.x == 0) {
    int nw = blockDim.x >> 6;
    float m = red[0];
    for (int i = 1; i < nw; i++) m = fmaxf(m, red[i]);
    atomicMax((unsigned int*)dst, __float_as_uint(m));
  }
}

__device__ __forceinline__ float amax_loop(const float* p, long n4, int bid, int gsz) {
  float am = 0.f;
  long i = (long)bid * blockDim.x + threadIdx.x;
  long stride = (long)gsz * blockDim.x;
  for (; i < n4; i += stride) {
    fx4 v = ((const fx4*)p)[i];
    #pragma unroll
    for (int j = 0; j < 4; j++) am = fmaxf(am, fabsf(v[j]));
  }
  return am;
}
// ---------- merged weight absmax (W1, W2, dw) ----------
__global__ void absmax_w(const float* __restrict__ W1, const float* __restrict__ W2,
                         const float* __restrict__ dwp, float* a) {
  int bx = blockIdx.x;
  float am; float* dst;
  if (bx < 256)      { am = amax_loop(W1,  131072, bx,       256); dst = a + 1; }
  else if (bx < 384) { am = amax_loop(W2,  65536,  bx - 256, 128); dst = a + 2; }
  else               { am = amax_loop(dwp, 3968,   bx - 384, 8);   dst = a + 3; }
  block_amax(am, dst);
}

// ---------- quantize fp32 [R x 512] -> integer-grid bf16 in MFMA-fragment-packed layout ----
// Packed: panel p=(r16,kb) (16 rows x 32 cols) stored as 64 chunks of 8 bf16;
// chunk c = quad*16+m16 holds row m16, cols kb*32+quad*8..+7. A wave's fragment
// load is then 64 lanes x 16B CONTIGUOUS (1KB panel) instead of 16 scattered rows.
__global__ void quant_pack(const float* __restrict__ src, bf16* __restrict__ dst,
                           int R, const float* amax) {
  float inv_s = 1.0f / dscale(amax);
  int total = R * 64;                       // one thread per 8-element chunk
  for (int t = blockIdx.x*blockDim.x + threadIdx.x; t < total; t += gridDim.x*blockDim.x) {
    int r = t >> 6, q8 = t & 63;            // read coalesced: row r, cols q8*8..+7
    const float* s = src + (size_t)r*512 + q8*8;
    fx4 v0 = *(const fx4*)s, v1 = *(const fx4*)(s+4);
    bf16x8 o;
    #pragma unroll
    for (int j = 0; j < 4; j++) { o[j] = (bf16)fq_int(v0[j], inv_s); o[4+j] = (bf16)fq_int(v1[j], inv_s); }
    int r16 = r >> 4, m16 = r & 15, kb = q8 >> 2, quad = q8 & 3;
    size_t chunk = ((size_t)r16*16 + kb)*64 + quad*16 + m16;
    ((bf16x8*)dst)[chunk] = o;
  }
}

// ---------- final fake-quant fp32 in place ----------
__global__ void quant_deq_f32(float* __restrict__ p, long n4, const float* amax) {
  float s = dscale(amax);
  float inv_s = 1.0f / s;
  long i = (long)blockIdx.x * blockDim.x + threadIdx.x;
  long stride = (long)gridDim.x * blockDim.x;
  for (; i < n4; i += stride) {
    fx4 v = ((fx4*)p)[i];
    fx4 o;
    #pragma unroll
    for (int j = 0; j < 4; j++) o[j] = fq_int(v[j], inv_s) * s;
    ((fx4*)p)[i] = o;
  }
}

// ---------- LayerNorm ----------
__global__ void ln_k(const float* __restrict__ x, const float* __restrict__ g,
                     const float* __restrict__ be, float* __restrict__ t, float* amax) {
  int lane = threadIdx.x & 63;
  int wavesTotal = (gridDim.x * blockDim.x) >> 6;
  int wave = ((blockIdx.x * blockDim.x) + threadIdx.x) >> 6;
  fx4 g0 = ((const fx4*)g)[lane],  g1 = ((const fx4*)g)[lane+64];
  fx4 b0 = ((const fx4*)be)[lane], b1v = ((const fx4*)be)[lane+64];
  float gf[8], bff[8];
  #pragma unroll
  for (int j = 0; j < 4; j++) { gf[j] = g0[j]; gf[4+j] = g1[j]; bff[j] = b0[j]; bff[4+j] = b1v[j]; }
  float am = 0.f;
  for (int row = wave; row < NM; row += wavesTotal) {
    const fx4* xr = (const fx4*)(x + (long)row*NF);
    fx4 x0 = xr[lane], x1 = xr[lane+64];
    float xf[8]; float s = 0.f;
    #pragma unroll
    for (int j = 0; j < 4; j++) { xf[j] = x0[j]; xf[4+j] = x1[j]; }
    #pragma unroll
    for (int j = 0; j < 8; j++) s += xf[j];
    #pragma unroll
    for (int o = 32; o > 0; o >>= 1) s += __shfl_xor(s, o);
    float mu = s * (1.0f/NF);
    float vs = 0.f;
    #pragma unroll
    for (int j = 0; j < 8; j++) { float d = xf[j]-mu; vs += d*d; }
    #pragma unroll
    for (int o = 32; o > 0; o >>= 1) vs += __shfl_xor(vs, o);
    float inv = rsqrtf(vs*(1.0f/NF) + EPSF);
    fx4 o0, o1;
    #pragma unroll
    for (int j = 0; j < 4; j++) {
      float v = (xf[j]-mu)*inv*gf[j] + bff[j];
      am = fmaxf(am, fabsf(v)); o0[j] = v;
    }
    #pragma unroll
    for (int j = 0; j < 4; j++) {
      float v = (xf[4+j]-mu)*inv*gf[4+j] + bff[4+j];
      am = fmaxf(am, fabsf(v)); o1[j] = v;
    }
    ((fx4*)(t + (long)row*NF))[lane]    = o0;
    ((fx4*)(t + (long)row*NF))[lane+64] = o1;
  }
  block_amax(am, amax);
}

// ---------- MFMA GEMM over fragment-packed operands (coalesced 1KB fragment loads) ----
// C[M,N] = (qA @ qBt^T)*sa*sb + bias; A,Bt packed per quant_pack. M=48000, K=512.
// 256 thr, 4 waves, 64x64/wave; no LDS, no K-loop barriers; XCD swizzle on grid.
template<int NBN>   // N = NBN*128
__global__ __launch_bounds__(256) void gemm_k(
    const bf16* __restrict__ A, const bf16* __restrict__ Bt,
    const float* __restrict__ bias, float* __restrict__ C,
    const float* amaxA, const float* amaxB, float* amaxC) {
  const int N = NBN * 128;
  int id = blockIdx.x;
  int bn = (id >> 3) % NBN;
  int bm = 8 * (id / (8 * NBN)) + (id & 7);
  if (bm >= 375) return;
  int lane = threadIdx.x & 63;
  int w = threadIdx.x >> 6;
  int wm = w >> 1, wn = w & 1;
  int quad = lane >> 4;
  int m16 = lane & 15;

  fx4 acc[4][4];
  #pragma unroll
  for (int i = 0; i < 4; i++)
    #pragma unroll
    for (int j = 0; j < 4; j++) acc[i][j] = fx4{0.f,0.f,0.f,0.f};

  const bf16* pA[4];
  const bf16* pB[4];
  #pragma unroll
  for (int i = 0; i < 4; i++)
    pA[i] = A + ((size_t)(bm*8 + wm*4 + i)*16)*512 + lane*8;   // panel base + lane chunk
  #pragma unroll
  for (int j = 0; j < 4; j++)
    pB[j] = Bt + ((size_t)(bn*8 + wn*4 + j)*16)*512 + lane*8;

  #pragma unroll
  for (int kb = 0; kb < 16; kb++) {
    s16x8 aF[4], bF[4];
    #pragma unroll
    for (int i = 0; i < 4; i++) aF[i] = *(const s16x8*)(pA[i] + kb*512);
    #pragma unroll
    for (int j = 0; j < 4; j++) bF[j] = *(const s16x8*)(pB[j] + kb*512);
    #pragma unroll
    for (int i = 0; i < 4; i++)
      #pragma unroll
      for (int j = 0; j < 4; j++)
        acc[i][j] = __builtin_amdgcn_mfma_f32_16x16x32_bf16(aF[i], bF[j], acc[i][j], 0, 0, 0);
  }

  float ab = dscale(amaxA) * dscale(amaxB);
  float am = 0.f;
  #pragma unroll
  for (int j = 0; j < 4; j++) {
    int col = bn*128 + wn*64 + j*16 + m16;
    float bv = bias[col];
    #pragma unroll
    for (int i = 0; i < 4; i++) {
      int row0 = bm*128 + wm*64 + i*16 + quad*4;
      #pragma unroll
      for (int rr = 0; rr < 4; rr++) {
        float v = acc[i][j][rr]*ab + bv;
        am = fmaxf(am, fabsf(v));
        C[(long)(row0+rr)*N + col] = v;
      }
    }
  }
  block_amax(am, amaxC);
}

// ---------- GLU + transpose [BT,1024] -> v[B,F,T] ----------
__global__ void glu_k(const float* __restrict__ u, float* __restrict__ v,
                      const float* amaxU, float* amaxV) {
  __shared__ float lds[32][33];
  float s = dscale(amaxU);
  float inv_s = 1.0f / s;
  float am = 0.f;
  int tx = threadIdx.x & 31, ty = threadIdx.x >> 5;   // 32 x 8
  const int ntile = (NM/32) * (NF/32);
  for (int tile = blockIdx.x; tile < ntile; tile += gridDim.x) {
    int btT = tile % (NM/32), fT = tile / (NM/32);
    int bt0 = btT*32, f0 = fT*32;
    __syncthreads();
    #pragma unroll
    for (int sI = 0; sI < 4; sI++) {
      int rr = ty + sI*8;
      long base = (long)(bt0 + rr)*(2*NF) + f0 + tx;
      float a = fq_int(u[base], inv_s) * s;
      float g = fq_int(u[base + NF], inv_s) * s;
      float val = a * (1.0f/(1.0f + expf(-g)));
      lds[tx][rr] = val;
      am = fmaxf(am, fabsf(val));
    }
    __syncthreads();
    #pragma unroll
    for (int sI = 0; sI < 4; sI++) {
      int f = f0 + ty + sI*8;
      int bt = bt0 + tx;
      int b = bt / NT, t = bt - b*NT;
      v[((long)b*NF + f)*NT + t] = lds[ty + sI*8][tx];
    }
  }
  block_amax(am, amaxV);
}

// ---------- depthwise conv K=31 on [B,F,T] ----------
__global__ void dwconv_k(const float* __restrict__ v, const float* __restrict__ w,
                         const float* __restrict__ wb, float* __restrict__ y,
                         const float* amaxV, const float* amaxW, float* amaxY) {
  __shared__ float z[NT + KW - 1];
  __shared__ float wl[KW];
  float sv = dscale(amaxV); float inv_sv = 1.0f/sv;
  float sw = dscale(amaxW); float inv_sw = 1.0f/sw;
  float am = 0.f;
  for (int row = blockIdx.x; row < NB*NF; row += gridDim.x) {
    int f = row & (NF-1);
    __syncthreads();
    if (threadIdx.x < KW)
      wl[threadIdx.x] = fq_int(w[f*KW + threadIdx.x], inv_sw) * sw;
    long base = (long)row * NT;
    for (int i = threadIdx.x; i < NT + KW - 1; i += 256) {
      int t = i - (KW-1)/2;
      float val = 0.f;
      if (t >= 0 && t < NT) val = fq_int(v[base + t], inv_sv) * sv;
      z[i] = val;
    }
    __syncthreads();
    float bias = wb[f];
    for (int t = threadIdx.x; t < NT; t += 256) {
      float acc = 0.f;
      #pragma unroll
      for (int k = 0; k < KW; k++) acc += z[t + k] * wl[k];
      acc += bias;
      am = fmaxf(am, fabsf(acc));
      y[base + t] = acc;
    }
  }
  block_amax(am, amaxY);
}

// ---------- BN stats: single pass, EXACT integer sums of quantized values ----------
__global__ void bnstats_k(const float* __restrict__ y, const float* amaxY,
                          float* bn_mean, float* bn_rinv) {
  float sy = dscale(amaxY); float inv_sy = 1.0f/sy;
  int f = blockIdx.x;
  int s1 = 0, s2 = 0;
  for (int b = 0; b < NB; b++) {
    const fx4* base = (const fx4*)(y + ((long)b*NF + f)*NT);
    for (int i = threadIdx.x; i < NT/4; i += blockDim.x) {
      fx4 v = base[i];
      #pragma unroll
      for (int j = 0; j < 4; j++) {
        int q = (int)fq_int(v[j], inv_sy);
        s1 += q; s2 += q*q;
      }
    }
  }
  #pragma unroll
  for (int o = 32; o > 0; o >>= 1) { s1 += __shfl_xor(s1, o); s2 += __shfl_xor(s2, o); }
  __shared__ int rs1[4], rs2[4];
  if ((threadIdx.x & 63) == 0) { rs1[threadIdx.x>>6] = s1; rs2[threadIdx.x>>6] = s2; }
  __syncthreads();
  if (threadIdx.x == 0) {
    long long S1 = (long long)rs1[0]+rs1[1]+rs1[2]+rs1[3];
    long long S2 = (long long)rs2[0]+rs2[1]+rs2[2]+rs2[3];
    double s = (double)sy;
    double mean = (double)S1 * s / (double)NM;
    double var  = (double)S2 * s * s / (double)NM - mean*mean;
    bn_mean[f] = (float)mean;
    bn_rinv[f] = rsqrtf((float)var + EPSF);
  }
}

// ---------- BN apply + silu + transpose [B,F,T] -> p[BT,F] ----------
__global__ void bnsilu_k(const float* __restrict__ y, const float* __restrict__ bg,
                         const float* __restrict__ bb, const float* amaxY,
                         const float* bn_mean, const float* bn_rinv,
                         float* __restrict__ p, float* amaxP) {
  __shared__ float lds[32][33];
  float sy = dscale(amaxY); float inv_sy = 1.0f/sy;
  float am = 0.f;
  int tx = threadIdx.x & 31, ty = threadIdx.x >> 5;
  const int TTILES = (NT + 31)/32;
  const int ntile = NB * (NF/32) * TTILES;
  for (int tile = blockIdx.x; tile < ntile; tile += gridDim.x) {
    int b = tile / ((NF/32)*TTILES);
    int rem = tile % ((NF/32)*TTILES);
    int fT = rem / TTILES, tT = rem % TTILES;
    int f0 = fT*32, t0 = tT*32;
    __syncthreads();
    #pragma unroll
    for (int sI = 0; sI < 4; sI++) {
      int f = f0 + ty + sI*8;
      int t = t0 + tx;
      if (t < NT) {
        float zq = fq_int(y[((long)b*NF + f)*NT + t], inv_sy) * sy;
        float val = (zq - bn_mean[f])*bn_rinv[f]*bg[f] + bb[f];
        val = val / (1.0f + expf(-val));
        am = fmaxf(am, fabsf(val));
        lds[tx][ty + sI*8] = val;
      }
    }
    __syncthreads();
    #pragma unroll
    for (int sI = 0; sI < 4; sI++) {
      int t = t0 + ty + sI*8;
      if (t < NT)
        p[((long)b*NT + t)*NF + f0 + tx] = lds[ty + sI*8][tx];
    }
  }
  block_amax(am, amaxP);
}

extern "C" void kernel_launch(void* const* d_in, const int* in_sizes, int n_in,
                              void* d_out, int out_size, void* d_ws, size_t ws_size,
                              hipStream_t stream) {
  const float* x  = (const float*)d_in[0];
  const float* lg = (const float*)d_in[1];
  const float* lb = (const float*)d_in[2];
  const float* W1 = (const float*)d_in[3];
  const float* b1 = (const float*)d_in[4];
  const float* dw = (const float*)d_in[5];
  const float* db = (const float*)d_in[6];
  const float* bg = (const float*)d_in[7];
  const float* bb = (const float*)d_in[8];
  const float* W2 = (const float*)d_in[9];
  const float* b2 = (const float*)d_in[10];
  float* out = (float*)d_out;

  char* ws = (char*)d_ws;
  float* amax    = (float*)ws;             // [0]=t [1]=W1 [2]=W2 [3]=dw [4]=u [5]=v [6]=y [7]=p [8]=r
  float* bn_mean = (float*)(ws + 1024);
  float* bn_rinv = (float*)(ws + 4096);
  char* H = ws + 8192;
  float* t_raw = (float*)H;                       // dies after pack
  float* u_raw = (float*)H;                       // [0, 196.6M)
  bf16*  t_q   = (bf16*)(H + 196608000);
  float* y     = (float*)H;                       // over dead u
  float* p_raw = (float*)(H + 98304000);
  bf16*  p_q   = (bf16*)(H + 196608000);          // over dead t_q
  bf16*  W1q   = (bf16*)(H + 245760000);
  bf16*  W2q   = (bf16*)(H + 246808576);
  float* v = (float*)d_out;
  float* r = (float*)d_out;

  hipMemsetAsync(ws, 0, 8192, stream);

  absmax_w<<<392, 256, 0, stream>>>(W1, W2, dw, amax);
  quant_pack<<<256, 256, 0, stream>>>(W1, W1q, 1024, amax+1);
  quant_pack<<<128, 256, 0, stream>>>(W2, W2q, 512,  amax+2);

  ln_k<<<1536, 256, 0, stream>>>(x, lg, lb, t_raw, amax+0);
  quant_pack<<<4096, 256, 0, stream>>>(t_raw, t_q, NM, amax+0);
  gemm_k<8><<<3008, 256, 0, stream>>>(t_q, W1q, b1, u_raw, amax+0, amax+1, amax+4);
  glu_k<<<4096, 256, 0, stream>>>(u_raw, v, amax+4, amax+5);
  dwconv_k<<<2048, 256, 0, stream>>>(v, dw, db, y, amax+5, amax+3, amax+6);
  bnstats_k<<<512, 256, 0, stream>>>(y, amax+6, bn_mean, bn_rinv);
  bnsilu_k<<<4096, 256, 0, stream>>>(y, bg, bb, amax+6, bn_mean, bn_rinv, p_raw, amax+7);
  quant_pack<<<4096, 256, 0, stream>>>(p_raw, p_q, NM, amax+7);
  gemm_k<4><<<1504, 256, 0, stream>>>(p_q, W2q, b2, r, amax+7, amax+2, amax+8);
  quant_deq_f32<<<2048, 256, 0, stream>>>(out, 24576000/4, amax+8);
}